// Round 5
// baseline (284.955 us; speedup 1.0000x reference)
//
#include <hip/hip_runtime.h>

#define BS 4
#define NF 512
#define HW 4096
#define C8 64
#define TI 64                       // i-rows per fused block
#define JC 32                       // j-chunk (R5: was 64; full-c, 2 blocks/CU)

typedef unsigned short bfu;                                    // raw bf16 bits
typedef __attribute__((ext_vector_type(8))) short bf16x8;      // MFMA A/B frag (4 VGPRs)
typedef __attribute__((ext_vector_type(4))) float f32x4;       // MFMA C/D frag

static __device__ __forceinline__ bfu f2bu(float v) {
    union { unsigned int u; float f; } c; c.f = v;
    unsigned int u = c.u;
    u = u + 0x7FFFu + ((u >> 16) & 1u);   // round-to-nearest-even
    return (bfu)(u >> 16);
}

// pack 2 f32 -> 2 bf16 (RNE), one instruction (T12 primitive; no builtin on gfx950)
static __device__ __forceinline__ unsigned int cvt_pk_bf16(float lo, float hi) {
    unsigned int r;
    asm("v_cvt_pk_bf16_f32 %0, %1, %2" : "=v"(r) : "v"(lo), "v"(hi));
    return r;
}

// async global->LDS, 16 B per lane (global_load_lds_dwordx4)
static __device__ __forceinline__ void gload16(const void* g, void* l) {
    __builtin_amdgcn_global_load_lds(
        (const __attribute__((address_space(1))) unsigned int*)g,
        (__attribute__((address_space(3))) unsigned int*)l,
        16, 0, 0);
}

// ---------------- k0: x fp32 [b][c][n] -> xt bf16 [b][n][c] ----------------
__global__ __launch_bounds__(256) void k0_xt(const float* __restrict__ x, bfu* __restrict__ xt)
{
    __shared__ float T[64][68];
    const int t  = threadIdx.x;
    const int n0 = blockIdx.x * 64;
    const int c0 = blockIdx.y * 64;
    const int b  = blockIdx.z;

    #pragma unroll
    for (int u = 0; u < 4; u++) {
        int f4 = u * 256 + t;
        int cc = f4 >> 4;
        int n4 = (f4 & 15) << 2;
        float4 v = *(const float4*)(x + ((size_t)(b * NF + c0 + cc)) * HW + n0 + n4);
        *(float4*)&T[cc][n4 ^ (((cc >> 3) & 3) << 2)] = v;     // group-XOR by row bits 3..4
    }
    __syncthreads();
    #pragma unroll
    for (int u = 0; u < 2; u++) {
        int e8 = u * 256 + t;
        int nn = e8 >> 3;
        int c8 = (e8 & 7) << 3;
        union { int4 i4; bfu h[8]; } pk;
        #pragma unroll
        for (int q = 0; q < 8; q++)
            pk.h[q] = f2bu(T[c8 + q][nn ^ ((((c8 + q) >> 3) & 3) << 2)]);
        *(int4*)(xt + ((size_t)(b * HW + n0 + nn)) * NF + c0 + c8) = pk.i4;
    }
}

// ---------------- k0b: Wq|Wk|Wv -> Wb bf16 [640][512]; biases -> bcat[640] ----------------
__global__ __launch_bounds__(256) void k0_w(const float* __restrict__ Wq, const float* __restrict__ bq,
                                            const float* __restrict__ Wk, const float* __restrict__ bk,
                                            const float* __restrict__ Wv, const float* __restrict__ bv,
                                            bfu* __restrict__ Wb, float* __restrict__ bcat)
{
    const int o = blockIdx.x;                   // 0..639
    const int t = threadIdx.x;
    const float* src; float bias;
    if (o < 64)       { src = Wq + (size_t)o * NF;          bias = bq[o]; }
    else if (o < 128) { src = Wk + (size_t)(o - 64) * NF;   bias = bk[o - 64]; }
    else              { src = Wv + (size_t)(o - 128) * NF;  bias = bv[o - 128]; }
    float2 v = *(const float2*)(src + t * 2);
    Wb[(size_t)o * NF + t * 2 + 0] = f2bu(v.x);
    Wb[(size_t)o * NF + t * 2 + 1] = f2bu(v.y);
    if (t == 0) bcat[o] = bias;
}

// ---------------- k1: Out[o][n] = Wb(640x512) . xt[b]^T, scatter into Qb/Kb/Vb ----------------
__global__ __launch_bounds__(256) void k1_proj(const bfu* __restrict__ Wb, const float* __restrict__ bcat,
                                               const bfu* __restrict__ xt,
                                               bfu* __restrict__ Qb, bfu* __restrict__ Kb, bfu* __restrict__ Vb)
{
    __shared__ bfu As[2][128 * 64];
    __shared__ bfu Bs[2][128 * 64];
    const int t  = threadIdx.x;
    const int o0 = blockIdx.x * 128;
    const int n0 = blockIdx.y * 128;
    const int b  = blockIdx.z;
    const int lane = t & 63, wv = t >> 6;
    const int wm = wv & 1, wn = wv >> 1;
    const int l15 = lane & 15, quad = lane >> 4;
    const int r7  = l15 & 7;
    const int sl0 = (quad ^ r7) * 8;            // swizzled slot, kk=0
    const int sl1 = ((quad + 4) ^ r7) * 8;      // swizzled slot, kk=32

    const int srow = t >> 3;                    // 0..31
    const int scolz = ((t & 7) ^ (srow & 7)) * 8;   // pre-swizzled source column

    const bfu* gA = Wb + ((size_t)(o0 + srow)) * NF + scolz;
    const bfu* gB = xt + ((size_t)(b * HW + n0 + srow)) * NF + scolz;

    f32x4 acc[4][4];
    #pragma unroll
    for (int m = 0; m < 4; m++)
        #pragma unroll
        for (int n = 0; n < 4; n++) acc[m][n] = (f32x4){0.f, 0.f, 0.f, 0.f};

#define K1_STAGE(buf, c0)                                                       \
    _Pragma("unroll")                                                           \
    for (int p = 0; p < 4; p++) {                                               \
        gload16(gA + (size_t)(p * 32) * NF + (c0), &As[buf][t * 8 + p * 2048]); \
        gload16(gB + (size_t)(p * 32) * NF + (c0), &Bs[buf][t * 8 + p * 2048]); \
    }

#define K1_COMPUTE(pc)                                                                      \
    {                                                                                       \
        bf16x8 Af0[4], Af1[4], Bf0[4], Bf1[4];                                              \
        _Pragma("unroll")                                                                   \
        for (int m = 0; m < 4; m++) {                                                       \
            const bfu* ar = &As[pc][(wm * 64 + m * 16 + l15) * 64];                         \
            Af0[m] = *(const bf16x8*)(ar + sl0);                                            \
            Af1[m] = *(const bf16x8*)(ar + sl1);                                            \
        }                                                                                   \
        _Pragma("unroll")                                                                   \
        for (int n = 0; n < 4; n++) {                                                       \
            const bfu* br = &Bs[pc][(wn * 64 + n * 16 + l15) * 64];                         \
            Bf0[n] = *(const bf16x8*)(br + sl0);                                            \
            Bf1[n] = *(const bf16x8*)(br + sl1);                                            \
        }                                                                                   \
        __builtin_amdgcn_s_setprio(1);                                                      \
        _Pragma("unroll")                                                                   \
        for (int m = 0; m < 4; m++)                                                         \
            _Pragma("unroll")                                                               \
            for (int n = 0; n < 4; n++) {                                                   \
                acc[m][n] = __builtin_amdgcn_mfma_f32_16x16x32_bf16(Af0[m], Bf0[n], acc[m][n], 0, 0, 0); \
                acc[m][n] = __builtin_amdgcn_mfma_f32_16x16x32_bf16(Af1[m], Bf1[n], acc[m][n], 0, 0, 0); \
            }                                                                               \
        __builtin_amdgcn_s_setprio(0);                                                      \
    }

    K1_STAGE(0, 0)                              // prologue: 8 vmem outstanding
    for (int it = 0; it < 7; it++) {
        const int pc = it & 1;
        K1_STAGE(pc ^ 1, (it + 1) * 64)         // +8 vmem -> 16
        asm volatile("s_waitcnt vmcnt(8)" ::: "memory");   // retire stage(it)
        __builtin_amdgcn_sched_barrier(0);
        __builtin_amdgcn_s_barrier();           // buf[pc] ready for all waves
        K1_COMPUTE(pc)
        __builtin_amdgcn_sched_barrier(0);
        __builtin_amdgcn_s_barrier();           // reads done -> restage ok
    }
    asm volatile("s_waitcnt vmcnt(0)" ::: "memory");
    __builtin_amdgcn_sched_barrier(0);
    __builtin_amdgcn_s_barrier();
    K1_COMPUTE(1)                               // c0 = 7 lives in buf 1
#undef K1_STAGE
#undef K1_COMPUTE

    if (o0 == 0) {
        #pragma unroll
        for (int mt = 0; mt < 4; mt++)
            #pragma unroll
            for (int nt = 0; nt < 4; nt++) {
                int goq = wm * 64 + mt * 16 + quad * 4;              // 0..124
                int n   = n0 + wn * 64 + nt * 16 + l15;
                float v0 = acc[mt][nt][0] + bcat[goq + 0];
                float v1 = acc[mt][nt][1] + bcat[goq + 1];
                float v2 = acc[mt][nt][2] + bcat[goq + 2];
                float v3 = acc[mt][nt][3] + bcat[goq + 3];
                int2 pk;
                pk.x = (int)cvt_pk_bf16(v0, v1);
                pk.y = (int)cvt_pk_bf16(v2, v3);
                if (wm == 0) *(int2*)(Qb + ((size_t)(b * HW + n)) * C8 + goq)      = pk;
                else         *(int2*)(Kb + ((size_t)(b * HW + n)) * C8 + goq - 64) = pk;
            }
    } else {
        #pragma unroll
        for (int mt = 0; mt < 4; mt++)
            #pragma unroll
            for (int nt = 0; nt < 4; nt++)
                #pragma unroll
                for (int r = 0; r < 4; r++) {
                    int go = o0 + wm * 64 + mt * 16 + quad * 4 + r;  // 128..639
                    int n  = n0 + wn * 64 + nt * 16 + l15;
                    float val = acc[mt][nt][r] + bcat[go];
                    Vb[((size_t)(b * NF + (go - 128))) * HW + n] = f2bu(val);
                }
    }
}

// ---------------- k23: fused scores + softmax-numerator + PV + residual ----------------
// R5: full-c block + JC=32 chunks. R4's c-split bought occupancy but (1)
// duplicated S+exp chip-wide x2 and (2) doubled P LDS re-read traffic per
// channel (LDS pipe ~1100 cy of the 2588-cy chunk = the largest consumer).
// Full c=512 with JC=32 gets 2 blocks/CU (Vs 2x32 KB + Ps 5 KB ~= 71 KB)
// with NO duplication and R3's efficient P-traffic rate.
// Roles (8 waves): S -> wave (iq=w>>1, jq=w&1) computes one 16x16 subtile
// (2 MFMA, 4 exps); PV -> wave owns c-slab w*64..+63: 16 MFMA, 4 V + 4 P
// b128 reads. Swizzles re-derived for 64-B V rows (slot ^ (row>>1)&3,
// pre-swizzled global source per rule #21) and Ps stride 40 (5 granules,
// coprime 8 -> 2 lanes/granule = b128 minimum). Pipeline: counted vmcnt(6)
// (4 stage + 2 Q per iter), raw barriers, setprio around PV (unchanged).
__global__ __launch_bounds__(512, 4) void k23_fused(const bfu* __restrict__ Kb, const bfu* __restrict__ Qb,
                                                    const bfu* __restrict__ Vb,
                                                    const float* __restrict__ x, const float* __restrict__ alpha,
                                                    float* __restrict__ out)
{
    __shared__ bfu   Vs[2][512 * JC];   // 2 x 32 KB, linear DMA dest; rows slot-swizzled
    __shared__ bfu   Ps[TI * 40];       // 5 KB P-tile [i][j], row stride 40 bfu (80 B)
    __shared__ float LSum[8][16];
    __shared__ float Scale[TI];

    const int t = threadIdx.x;
    const int lane = t & 63, w = t >> 6;
    const int l15 = lane & 15, quad = lane >> 4;
    const int iq = w >> 1, jq = w & 1;  // S-role: one 16x16 subtile
    const int cw = w * 64;              // PV slab: channels cw..cw+63

    // XCD pinning: 256 blocks, d&7 -> XCD; XCDs {2b,2b+1} own batch b.
    const int d    = blockIdx.x;        // 0..255
    const int xcd  = d & 7;
    const int b    = xcd >> 1;
    const int i0   = ((xcd & 1) * 32 + (d >> 3)) * TI;

    // persistent K fragments (B-side of S-MFMA): i = i0 + iq*16 + l15
    const bfu* kp = Kb + ((size_t)(b * HW + i0 + iq * 16 + l15)) * C8 + quad * 8;
    const bf16x8 Kf0 = *(const bf16x8*)kp;
    const bf16x8 Kf1 = *(const bf16x8*)(kp + 32);

    // V staging: thread t fills LDS rows (t>>2)+128p at slot (t&3); global
    // column pre-swizzled (slot ^ (row>>1)&3) so the linear DMA dest receives
    // the swizzled layout. (row>>1)&3 = (t>>3)&3, invariant under +128p.
    const int srow = t >> 2;
    const bfu* gV = Vb + ((size_t)(b * NF + srow)) * HW + (((t & 3) ^ ((t >> 3) & 3)) * 8);

    // Q stream base (A-side of S-MFMA): j = jb + jq*16 + l15
    const bfu* qbase = Qb + ((size_t)(b * HW + jq * 16 + l15)) * C8 + quad * 8;

    // swizzled V read slot: row = cw + mt*16 + l15 -> (row>>1)&3 = (l15>>1)&3
    const int vsl = (quad ^ ((l15 >> 1) & 3)) * 8;

    f32x4 acc[4][4];
    #pragma unroll
    for (int mt = 0; mt < 4; mt++)
        #pragma unroll
        for (int nt = 0; nt < 4; nt++) acc[mt][nt] = (f32x4){0.f, 0.f, 0.f, 0.f};
    float rs = 0.f;
    bf16x8 Aq[2][2];                    // Q frag double-buffer [parity][half]

    // prologue: stage chunk 0 into Vs[0], prefetch Q(0).
    // vmem order: Kf x2, stage(0) x4, Q(0) x2 -> 8 outstanding.
    {
        #pragma unroll
        for (int p = 0; p < 4; p++)
            gload16(gV + (size_t)(p * 128) * HW, &Vs[0][t * 8 + p * 4096]);
        Aq[0][0] = *(const bf16x8*)qbase;
        Aq[0][1] = *(const bf16x8*)(qbase + 32);
    }

// one pipelined chunk iteration; pc/pn are compile-time parities (rule #20)
#define K23_ITER(q, pc, pn)                                                                    \
  {                                                                                            \
    const int jn = (((q) + 1) & 127) * JC;                                                     \
    /* stage chunk q+1 into buf pn (4 vmem) + prefetch Q(q+1) (2 vmem) */                      \
    _Pragma("unroll")                                                                          \
    for (int p = 0; p < 4; p++)                                                                \
        gload16(gV + (size_t)(p * 128) * HW + jn, &Vs[pn][t * 8 + p * 4096]);                  \
    {                                                                                          \
        const bfu* qpn = qbase + (size_t)jn * C8;                                              \
        Aq[pn][0] = *(const bf16x8*)qpn;                                                       \
        Aq[pn][1] = *(const bf16x8*)(qpn + 32);                                                \
    }                                                                                          \
    /* retire the previous iter's 6 (stage(q)+Q(q)); this iter's 6 stay in flight */           \
    asm volatile("s_waitcnt vmcnt(6)" ::: "memory");                                           \
    __builtin_amdgcn_sched_barrier(0);                                                         \
    /* S-step: one 16x16 subtile D[j][i] = Q[j][c].K[i][c] */                                  \
    {                                                                                          \
        f32x4 s = (f32x4){0.f,0.f,0.f,0.f};                                                    \
        s = __builtin_amdgcn_mfma_f32_16x16x32_bf16(Aq[pc][0], Kf0, s, 0, 0, 0);               \
        s = __builtin_amdgcn_mfma_f32_16x16x32_bf16(Aq[pc][1], Kf1, s, 0, 0, 0);               \
        float e0 = __expf(s[0]), e1 = __expf(s[1]), e2 = __expf(s[2]), e3 = __expf(s[3]);      \
        rs += (e0 + e1) + (e2 + e3);                                                           \
        uint2 pk;                                                                              \
        pk.x = cvt_pk_bf16(e0, e1);  pk.y = cvt_pk_bf16(e2, e3);                               \
        *(uint2*)(Ps + (iq * 16 + l15) * 40 + jq * 16 + quad * 4) = pk;                        \
    }                                                                                          \
    asm volatile("s_waitcnt lgkmcnt(0)" ::: "memory");                                         \
    __builtin_amdgcn_sched_barrier(0);                                                         \
    __builtin_amdgcn_s_barrier();   /* Vs[pc] staged by all + Ps visible */                    \
    /* PV: D[c][i] += V[c][j].P[i][j] from buf pc (K = JC = 32, one depth) */                  \
    {                                                                                          \
        bf16x8 Pf[4];                                                                          \
        _Pragma("unroll")                                                                      \
        for (int nt = 0; nt < 4; nt++)                                                         \
            Pf[nt] = *(const bf16x8*)(Ps + (nt * 16 + l15) * 40 + quad * 8);                   \
        __builtin_amdgcn_s_setprio(1);                                                         \
        _Pragma("unroll")                                                                      \
        for (int mt = 0; mt < 4; mt++) {                                                       \
            const bf16x8 Vf = *(const bf16x8*)(&Vs[pc][(cw + mt * 16 + l15) * JC] + vsl);      \
            _Pragma("unroll")                                                                  \
            for (int nt = 0; nt < 4; nt++)                                                     \
                acc[mt][nt] = __builtin_amdgcn_mfma_f32_16x16x32_bf16(Vf, Pf[nt], acc[mt][nt], 0, 0, 0); \
        }                                                                                      \
        __builtin_amdgcn_s_setprio(0);                                                         \
    }                                                                                          \
    __builtin_amdgcn_sched_barrier(0);                                                         \
    __builtin_amdgcn_s_barrier();   /* all PV reads of Vs[pc]/Ps done -> restage/rewrite ok */ \
  }

    for (int qq = 0; qq < 64; qq++) {
        K23_ITER(2 * qq,     0, 1)
        K23_ITER(2 * qq + 1, 1, 0)
    }
#undef K23_ITER

    // row-sum: lane's rs covers i = i0 + iq*16 + l15, j in its (jq,quad,r) set
    float sred = rs;
    sred += __shfl_xor(sred, 16, 64);
    sred += __shfl_xor(sred, 32, 64);
    if (quad == 0) LSum[w][l15] = sred;
    __syncthreads();
    if (t < TI) {
        int iqq = t >> 4, il = t & 15;
        float L = LSum[iqq * 2 + 0][il] + LSum[iqq * 2 + 1][il];
        Scale[t] = alpha[0] / L;
    }
    __syncthreads();

    #pragma unroll
    for (int nt = 0; nt < 4; nt++) {
        float sc = Scale[nt * 16 + l15];
        int i = i0 + nt * 16 + l15;
        #pragma unroll
        for (int mt = 0; mt < 4; mt++)
            #pragma unroll
            for (int r = 0; r < 4; r++) {
                int c = cw + mt * 16 + quad * 4 + r;
                size_t idx = ((size_t)(b * NF + c)) * HW + i;
                out[idx] = x[idx] + sc * acc[mt][nt][r];
            }
    }
}

extern "C" void kernel_launch(void* const* d_in, const int* in_sizes, int n_in,
                              void* d_out, int out_size, void* d_ws, size_t ws_size,
                              hipStream_t stream)
{
    const float* x     = (const float*)d_in[0];
    const float* Wq    = (const float*)d_in[1];
    const float* bq    = (const float*)d_in[2];
    const float* Wk    = (const float*)d_in[3];
    const float* bk    = (const float*)d_in[4];
    const float* Wv    = (const float*)d_in[5];
    const float* bv    = (const float*)d_in[6];
    const float* alpha = (const float*)d_in[7];
    float* out = (float*)d_out;

    char* ws = (char*)d_ws;
    bfu*   xt   = (bfu*)(ws);                                  // [0,16) MB : [b][n][c] bf16
    bfu*   Wb   = (bfu*)(ws + (16u << 20));                    // [16,~16.6) MB: [640][512] bf16
    float* bcat = (float*)(ws + (17u << 20));                  // 2.5 KB at 17 MB
    bfu*   Qb   = (bfu*)(ws + (18u << 20));                    // [18,20) MB : [b][n][64]
    bfu*   Kb   = (bfu*)(ws + (20u << 20));                    // [20,22) MB : [b][n][64]
    bfu*   Vb   = (bfu*)(ws + (22u << 20));                    // [22,38) MB : [b][c][n]  (16 MB)

    k0_xt<<<dim3(HW / 64, NF / 64, BS), 256, 0, stream>>>(x, xt);
    k0_w<<<dim3(640), 256, 0, stream>>>(Wq, bq, Wk, bk, Wv, bv, Wb, bcat);
    k1_proj<<<dim3(5, HW / 128, BS), 256, 0, stream>>>(Wb, bcat, xt, Qb, Kb, Vb);
    k23_fused<<<dim3(HW / TI * BS), 512, 0, stream>>>(Kb, Qb, Vb, x, alpha, out);
}

// Round 6
// 218.820 us; speedup vs baseline: 1.3022x; 1.3022x over previous
//
#include <hip/hip_runtime.h>

#define BS 4
#define NF 512
#define HW 4096
#define C8 64
#define TI 64                       // i-rows per fused block
#define JC 64                       // j-chunk

typedef unsigned short bfu;                                    // raw bf16 bits
typedef __attribute__((ext_vector_type(8))) short bf16x8;      // MFMA A/B frag (4 VGPRs)
typedef __attribute__((ext_vector_type(4))) float f32x4;       // MFMA C/D frag

static __device__ __forceinline__ bfu f2bu(float v) {
    union { unsigned int u; float f; } c; c.f = v;
    unsigned int u = c.u;
    u = u + 0x7FFFu + ((u >> 16) & 1u);   // round-to-nearest-even
    return (bfu)(u >> 16);
}

// pack 2 f32 -> 2 bf16 (RNE), one instruction (T12 primitive; no builtin on gfx950)
static __device__ __forceinline__ unsigned int cvt_pk_bf16(float lo, float hi) {
    unsigned int r;
    asm("v_cvt_pk_bf16_f32 %0, %1, %2" : "=v"(r) : "v"(lo), "v"(hi));
    return r;
}

// async global->LDS, 16 B per lane (global_load_lds_dwordx4)
static __device__ __forceinline__ void gload16(const void* g, void* l) {
    __builtin_amdgcn_global_load_lds(
        (const __attribute__((address_space(1))) unsigned int*)g,
        (__attribute__((address_space(3))) unsigned int*)l,
        16, 0, 0);
}

// ---------------- k0_pre: x transpose (2048 blocks) + weight prep (640 blocks) merged ----------
__global__ __launch_bounds__(256) void k0_pre(const float* __restrict__ x, bfu* __restrict__ xt,
                                              const float* __restrict__ Wq, const float* __restrict__ bq,
                                              const float* __restrict__ Wk, const float* __restrict__ bk,
                                              const float* __restrict__ Wv, const float* __restrict__ bv,
                                              bfu* __restrict__ Wb, float* __restrict__ bcat)
{
    __shared__ float T[64][68];
    const int t   = threadIdx.x;
    const int bid = blockIdx.x;

    if (bid >= 2048) {                          // weight-prep blocks (old k0_w)
        const int o = bid - 2048;               // 0..639
        const float* src; float bias;
        if (o < 64)       { src = Wq + (size_t)o * NF;          bias = bq[o]; }
        else if (o < 128) { src = Wk + (size_t)(o - 64) * NF;   bias = bk[o - 64]; }
        else              { src = Wv + (size_t)(o - 128) * NF;  bias = bv[o - 128]; }
        float2 v = *(const float2*)(src + t * 2);
        Wb[(size_t)o * NF + t * 2 + 0] = f2bu(v.x);
        Wb[(size_t)o * NF + t * 2 + 1] = f2bu(v.y);
        if (t == 0) bcat[o] = bias;
        return;
    }

    const int n0 = (bid & 63) * 64;
    const int c0 = ((bid >> 6) & 7) * 64;
    const int b  = bid >> 9;

    #pragma unroll
    for (int u = 0; u < 4; u++) {
        int f4 = u * 256 + t;
        int cc = f4 >> 4;
        int n4 = (f4 & 15) << 2;
        float4 v = *(const float4*)(x + ((size_t)(b * NF + c0 + cc)) * HW + n0 + n4);
        *(float4*)&T[cc][n4 ^ (((cc >> 3) & 3) << 2)] = v;     // group-XOR by row bits 3..4
    }
    __syncthreads();
    #pragma unroll
    for (int u = 0; u < 2; u++) {
        int e8 = u * 256 + t;
        int nn = e8 >> 3;
        int c8 = (e8 & 7) << 3;
        union { int4 i4; bfu h[8]; } pk;
        #pragma unroll
        for (int q = 0; q < 8; q++)
            pk.h[q] = f2bu(T[c8 + q][nn ^ ((((c8 + q) >> 3) & 3) << 2)]);
        *(int4*)(xt + ((size_t)(b * HW + n0 + nn)) * NF + c0 + c8) = pk.i4;
    }
}

// ---------------- k1: Out[o][n] = Wb(640x512) . xt[b]^T, scatter into Qb/Kb/Vb ----------------
// R4 pipelined version (counted vmcnt, XOR-swizzled tiles, packed Q/K stores).
__global__ __launch_bounds__(256) void k1_proj(const bfu* __restrict__ Wb, const float* __restrict__ bcat,
                                               const bfu* __restrict__ xt,
                                               bfu* __restrict__ Qb, bfu* __restrict__ Kb, bfu* __restrict__ Vb)
{
    __shared__ bfu As[2][128 * 64];
    __shared__ bfu Bs[2][128 * 64];
    const int t  = threadIdx.x;
    const int o0 = blockIdx.x * 128;
    const int n0 = blockIdx.y * 128;
    const int b  = blockIdx.z;
    const int lane = t & 63, wv = t >> 6;
    const int wm = wv & 1, wn = wv >> 1;
    const int l15 = lane & 15, quad = lane >> 4;
    const int r7  = l15 & 7;
    const int sl0 = (quad ^ r7) * 8;            // swizzled slot, kk=0
    const int sl1 = ((quad + 4) ^ r7) * 8;      // swizzled slot, kk=32

    const int srow = t >> 3;                    // 0..31
    const int scolz = ((t & 7) ^ (srow & 7)) * 8;   // pre-swizzled source column

    const bfu* gA = Wb + ((size_t)(o0 + srow)) * NF + scolz;
    const bfu* gB = xt + ((size_t)(b * HW + n0 + srow)) * NF + scolz;

    f32x4 acc[4][4];
    #pragma unroll
    for (int m = 0; m < 4; m++)
        #pragma unroll
        for (int n = 0; n < 4; n++) acc[m][n] = (f32x4){0.f, 0.f, 0.f, 0.f};

#define K1_STAGE(buf, c0)                                                       \
    _Pragma("unroll")                                                           \
    for (int p = 0; p < 4; p++) {                                               \
        gload16(gA + (size_t)(p * 32) * NF + (c0), &As[buf][t * 8 + p * 2048]); \
        gload16(gB + (size_t)(p * 32) * NF + (c0), &Bs[buf][t * 8 + p * 2048]); \
    }

#define K1_COMPUTE(pc)                                                                      \
    {                                                                                       \
        bf16x8 Af0[4], Af1[4], Bf0[4], Bf1[4];                                              \
        _Pragma("unroll")                                                                   \
        for (int m = 0; m < 4; m++) {                                                       \
            const bfu* ar = &As[pc][(wm * 64 + m * 16 + l15) * 64];                         \
            Af0[m] = *(const bf16x8*)(ar + sl0);                                            \
            Af1[m] = *(const bf16x8*)(ar + sl1);                                            \
        }                                                                                   \
        _Pragma("unroll")                                                                   \
        for (int n = 0; n < 4; n++) {                                                       \
            const bfu* br = &Bs[pc][(wn * 64 + n * 16 + l15) * 64];                         \
            Bf0[n] = *(const bf16x8*)(br + sl0);                                            \
            Bf1[n] = *(const bf16x8*)(br + sl1);                                            \
        }                                                                                   \
        __builtin_amdgcn_s_setprio(1);                                                      \
        _Pragma("unroll")                                                                   \
        for (int m = 0; m < 4; m++)                                                         \
            _Pragma("unroll")                                                               \
            for (int n = 0; n < 4; n++) {                                                   \
                acc[m][n] = __builtin_amdgcn_mfma_f32_16x16x32_bf16(Af0[m], Bf0[n], acc[m][n], 0, 0, 0); \
                acc[m][n] = __builtin_amdgcn_mfma_f32_16x16x32_bf16(Af1[m], Bf1[n], acc[m][n], 0, 0, 0); \
            }                                                                               \
        __builtin_amdgcn_s_setprio(0);                                                      \
    }

    K1_STAGE(0, 0)                              // prologue: 8 vmem outstanding
    for (int it = 0; it < 7; it++) {
        const int pc = it & 1;
        K1_STAGE(pc ^ 1, (it + 1) * 64)         // +8 vmem -> 16
        asm volatile("s_waitcnt vmcnt(8)" ::: "memory");   // retire stage(it)
        __builtin_amdgcn_sched_barrier(0);
        __builtin_amdgcn_s_barrier();           // buf[pc] ready for all waves
        K1_COMPUTE(pc)
        __builtin_amdgcn_sched_barrier(0);
        __builtin_amdgcn_s_barrier();           // reads done -> restage ok
    }
    asm volatile("s_waitcnt vmcnt(0)" ::: "memory");
    __builtin_amdgcn_sched_barrier(0);
    __builtin_amdgcn_s_barrier();
    K1_COMPUTE(1)                               // c0 = 7 lives in buf 1
#undef K1_STAGE
#undef K1_COMPUTE

    if (o0 == 0) {
        #pragma unroll
        for (int mt = 0; mt < 4; mt++)
            #pragma unroll
            for (int nt = 0; nt < 4; nt++) {
                int goq = wm * 64 + mt * 16 + quad * 4;              // 0..124
                int n   = n0 + wn * 64 + nt * 16 + l15;
                float v0 = acc[mt][nt][0] + bcat[goq + 0];
                float v1 = acc[mt][nt][1] + bcat[goq + 1];
                float v2 = acc[mt][nt][2] + bcat[goq + 2];
                float v3 = acc[mt][nt][3] + bcat[goq + 3];
                int2 pk;
                pk.x = (int)cvt_pk_bf16(v0, v1);
                pk.y = (int)cvt_pk_bf16(v2, v3);
                if (wm == 0) *(int2*)(Qb + ((size_t)(b * HW + n)) * C8 + goq)      = pk;
                else         *(int2*)(Kb + ((size_t)(b * HW + n)) * C8 + goq - 64) = pk;
            }
    } else {
        #pragma unroll
        for (int mt = 0; mt < 4; mt++)
            #pragma unroll
            for (int nt = 0; nt < 4; nt++)
                #pragma unroll
                for (int r = 0; r < 4; r++) {
                    int go = o0 + wm * 64 + mt * 16 + quad * 4 + r;  // 128..639
                    int n  = n0 + wn * 64 + nt * 16 + l15;
                    float val = acc[mt][nt][r] + bcat[go];
                    Vb[((size_t)(b * NF + (go - 128))) * HW + n] = f2bu(val);
                }
    }
}

// ---------------- k23: fused scores + softmax-numerator + PV + residual ----------------
// R6: R4 geometry (TI=64, JC=64, c-split 2, grid 512, 2 blocks/CU — proven 138 us)
// with the chunk phases restructured so nothing serial sits between the barriers:
//   B1 (Vs[pc]+Ps(q) ready) -> S-MFMAs for chunk q+1 issued first (register-only,
//   results consumed AFTER B2 -> latency matures under PV; T15 mechanism) ->
//   Pf/Vf reads + PV MFMAs -> lgkm(0) -> B2 (all LDS reads done => Ps writable,
//   Vs[pc] restageable) -> exp/cvt_pk/Ps-write AFTER B2, overlapping next iter's
//   stage issue. The exp chain (~150 cy of transcendental VALU) leaves the
//   inter-barrier critical path entirely.
// Ps: single 8 KB buffer [64][64], XOR slot-swizzle (slot ^ row&7) instead of
// R4's pad-72 (kills the residual Ps bank conflicts). Both-sides swizzle on
// Vs unchanged (rule #21). vmcnt ledger: iter issues Q(q+1) [2] then stage(q+1)
// [4]; vmcnt(6) at B1 retires stage(q); compiler's own wait covers Aq use.
__global__ __launch_bounds__(512, 4) void k23_fused(const bfu* __restrict__ Kb, const bfu* __restrict__ Qb,
                                                    const bfu* __restrict__ Vb,
                                                    const float* __restrict__ x, const float* __restrict__ alpha,
                                                    float* __restrict__ out)
{
    __shared__ bfu   Vs[2][256 * 64];   // 2 x 32 KB, linear DMA dest; rows slot-swizzled
    __shared__ bfu   Ps[64 * 64];       // 8 KB P-tile [i][j], slot-swizzled, no pad
    __shared__ float LSum[8][2][16];
    __shared__ float Scale[TI];

    const int t = threadIdx.x;
    const int lane = t & 63, w = t >> 6;
    const int l15 = lane & 15, quad = lane >> 4;
    const int jq  = w & 3;              // S-role: j-subtile
    const int iqb = (w >> 2) * 32;      // S-role: 32-row i-slab (two 16-row subtiles)

    // XCD pinning: d&7 -> XCD; b = xcd>>1, cblk = xcd&1; i0 from d>>3.
    const int d    = blockIdx.x;        // 0..511
    const int xcd  = d & 7;
    const int b    = xcd >> 1;
    const int cblk = xcd & 1;           // which 256-channel half of V/out
    const int i0   = (d >> 3) * TI;     // 0..4032

    // persistent K fragments (B-side of S-MFMA), two i-subtiles
    const bfu* kp0 = Kb + ((size_t)(b * HW + i0 + iqb + l15)) * C8 + quad * 8;
    const bfu* kp1 = kp0 + (size_t)16 * C8;
    const bf16x8 Kf00 = *(const bf16x8*)kp0;
    const bf16x8 Kf01 = *(const bf16x8*)(kp0 + 32);
    const bf16x8 Kf10 = *(const bf16x8*)kp1;
    const bf16x8 Kf11 = *(const bf16x8*)(kp1 + 32);

    // V staging: thread t fills rows (t>>3)+64p at slot (t&7); global column
    // pre-swizzled (slot ^ row&7) so linear DMA dest gets the swizzled layout.
    const int srow = t >> 3, sslot = t & 7;
    const bfu* gV = Vb + ((size_t)(b * NF + cblk * 256 + srow)) * HW + ((sslot ^ (srow & 7)) * 8);

    // Q stream base (A-side of S-MFMA): j = jb + jq*16 + l15
    const bfu* qbase = Qb + ((size_t)(b * HW + jq * 16 + l15)) * C8 + quad * 8;

    const int r7  = l15 & 7;
    const int sl0 = (quad ^ r7) * 8;            // swizzled 16B slot, kk=0 (Vs rows & Ps rows both have row&7==l15&7)
    const int sl1 = ((quad + 4) ^ r7) * 8;      // kk=1
    // Ps write offset: col granule jq*16+quad*4 -> slot jq*2+(quad>>1), sub (quad&1)*4 elems
    const int pwz = ((jq * 2 + (quad >> 1)) ^ r7) * 8 + (quad & 1) * 4;

    f32x4 acc[2][4];
    #pragma unroll
    for (int mt = 0; mt < 2; mt++)
        #pragma unroll
        for (int nt = 0; nt < 4; nt++) acc[mt][nt] = (f32x4){0.f, 0.f, 0.f, 0.f};
    float rs0 = 0.f, rs1 = 0.f;
    bf16x8 Aq[2][2];                    // Q frag double-buffer [parity][half]

    // prologue: Q(0), stage(0) -> Vs[0], S(0) -> Ps. (compiler inserts the
    // vmcnt for Kf/Aq use; stage(0) rides through to the loop's vmcnt(6))
    Aq[0][0] = *(const bf16x8*)qbase;
    Aq[0][1] = *(const bf16x8*)(qbase + 32);
    #pragma unroll
    for (int p = 0; p < 4; p++)
        gload16(gV + (size_t)(p * 64) * HW, &Vs[0][t * 8 + p * 4096]);
    {
        f32x4 s0 = (f32x4){0.f,0.f,0.f,0.f}, s1 = (f32x4){0.f,0.f,0.f,0.f};
        s0 = __builtin_amdgcn_mfma_f32_16x16x32_bf16(Aq[0][0], Kf00, s0, 0, 0, 0);
        s0 = __builtin_amdgcn_mfma_f32_16x16x32_bf16(Aq[0][1], Kf01, s0, 0, 0, 0);
        s1 = __builtin_amdgcn_mfma_f32_16x16x32_bf16(Aq[0][0], Kf10, s1, 0, 0, 0);
        s1 = __builtin_amdgcn_mfma_f32_16x16x32_bf16(Aq[0][1], Kf11, s1, 0, 0, 0);
        float e0 = __expf(s0[0]), e1 = __expf(s0[1]), e2 = __expf(s0[2]), e3 = __expf(s0[3]);
        float f0 = __expf(s1[0]), f1 = __expf(s1[1]), f2 = __expf(s1[2]), f3 = __expf(s1[3]);
        rs0 += (e0 + e1) + (e2 + e3);
        rs1 += (f0 + f1) + (f2 + f3);
        uint2 pk0, pk1;
        pk0.x = cvt_pk_bf16(e0, e1);  pk0.y = cvt_pk_bf16(e2, e3);
        pk1.x = cvt_pk_bf16(f0, f1);  pk1.y = cvt_pk_bf16(f2, f3);
        *(uint2*)(Ps + (iqb + l15)      * 64 + pwz) = pk0;
        *(uint2*)(Ps + (iqb + 16 + l15) * 64 + pwz) = pk1;
    }

// one pipelined chunk iteration; pc/pn compile-time parities (rule #20)
#define K23_ITER(q, pc, pn)                                                                    \
  {                                                                                            \
    const int jn = (((q) + 1) & 63) * JC;                                                      \
    /* prefetch Q(q+1) [2 vmem] BEFORE stage(q+1) [4 vmem] */                                  \
    {                                                                                          \
        const bfu* qpn = qbase + (size_t)jn * C8;                                              \
        Aq[pn][0] = *(const bf16x8*)qpn;                                                       \
        Aq[pn][1] = *(const bf16x8*)(qpn + 32);                                                \
    }                                                                                          \
    _Pragma("unroll")                                                                          \
    for (int p = 0; p < 4; p++)                                                                \
        gload16(gV + (size_t)(p * 64) * HW + jn, &Vs[pn][t * 8 + p * 4096]);                   \
    /* retire stage(q); Q(q+1)+stage(q+1) stay in flight; lgkm: prev Ps writes done */         \
    asm volatile("s_waitcnt vmcnt(6) lgkmcnt(0)" ::: "memory");                                \
    __builtin_amdgcn_sched_barrier(0);                                                         \
    __builtin_amdgcn_s_barrier();   /* B1: Vs[pc] staged, Ps(q) visible */                     \
    /* S-MFMAs for chunk q+1 first: register-only, results consumed after B2 */                \
    f32x4 s0 = (f32x4){0.f,0.f,0.f,0.f}, s1 = (f32x4){0.f,0.f,0.f,0.f};                        \
    if (jn) {                                                                                  \
        s0 = __builtin_amdgcn_mfma_f32_16x16x32_bf16(Aq[pn][0], Kf00, s0, 0, 0, 0);            \
        s0 = __builtin_amdgcn_mfma_f32_16x16x32_bf16(Aq[pn][1], Kf01, s0, 0, 0, 0);            \
        s1 = __builtin_amdgcn_mfma_f32_16x16x32_bf16(Aq[pn][0], Kf10, s1, 0, 0, 0);            \
        s1 = __builtin_amdgcn_mfma_f32_16x16x32_bf16(Aq[pn][1], Kf11, s1, 0, 0, 0);            \
    }                                                                                          \
    /* PV: hold V frags, stream Pf per nt (keeps VGPR ~115) */                                 \
    {                                                                                          \
        bf16x8 V0[2], V1[2];                                                                   \
        _Pragma("unroll")                                                                      \
        for (int mt = 0; mt < 2; mt++) {                                                       \
            const bfu* vrow = &Vs[pc][(w * 32 + mt * 16 + l15) * 64];                          \
            V0[mt] = *(const bf16x8*)(vrow + sl0);                                             \
            V1[mt] = *(const bf16x8*)(vrow + sl1);                                             \
        }                                                                                      \
        __builtin_amdgcn_s_setprio(1);                                                         \
        _Pragma("unroll")                                                                      \
        for (int nt = 0; nt < 4; nt++) {                                                       \
            const bfu* prow = Ps + (nt * 16 + l15) * 64;                                       \
            bf16x8 Pf0 = *(const bf16x8*)(prow + sl0);                                         \
            bf16x8 Pf1 = *(const bf16x8*)(prow + sl1);                                         \
            _Pragma("unroll")                                                                  \
            for (int mt = 0; mt < 2; mt++) {                                                   \
                acc[mt][nt] = __builtin_amdgcn_mfma_f32_16x16x32_bf16(V0[mt], Pf0, acc[mt][nt], 0, 0, 0); \
                acc[mt][nt] = __builtin_amdgcn_mfma_f32_16x16x32_bf16(V1[mt], Pf1, acc[mt][nt], 0, 0, 0); \
            }                                                                                  \
        }                                                                                      \
        __builtin_amdgcn_s_setprio(0);                                                         \
    }                                                                                          \
    asm volatile("s_waitcnt lgkmcnt(0)" ::: "memory");                                         \
    __builtin_amdgcn_sched_barrier(0);                                                         \
    __builtin_amdgcn_s_barrier();   /* B2: all Ps/Vs reads done -> writable/restageable */     \
    /* softmax finish for chunk q+1: off the inter-barrier path */                             \
    if (jn) {                                                                                  \
        float e0 = __expf(s0[0]), e1 = __expf(s0[1]), e2 = __expf(s0[2]), e3 = __expf(s0[3]);  \
        float f0 = __expf(s1[0]), f1 = __expf(s1[1]), f2 = __expf(s1[2]), f3 = __expf(s1[3]);  \
        rs0 += (e0 + e1) + (e2 + e3);                                                          \
        rs1 += (f0 + f1) + (f2 + f3);                                                          \
        uint2 pk0, pk1;                                                                        \
        pk0.x = cvt_pk_bf16(e0, e1);  pk0.y = cvt_pk_bf16(e2, e3);                             \
        pk1.x = cvt_pk_bf16(f0, f1);  pk1.y = cvt_pk_bf16(f2, f3);                             \
        *(uint2*)(Ps + (iqb + l15)      * 64 + pwz) = pk0;                                     \
        *(uint2*)(Ps + (iqb + 16 + l15) * 64 + pwz) = pk1;                                     \
    }                                                                                          \
  }

    for (int qq = 0; qq < 32; qq++) {
        K23_ITER(2 * qq,     0, 1)
        K23_ITER(2 * qq + 1, 1, 0)
    }
#undef K23_ITER

    // row-sum reduction: rs0/rs1 cover i = i0 + iqb + {0,16} + l15
    float sred0 = rs0, sred1 = rs1;
    sred0 += __shfl_xor(sred0, 16, 64);
    sred0 += __shfl_xor(sred0, 32, 64);
    sred1 += __shfl_xor(sred1, 16, 64);
    sred1 += __shfl_xor(sred1, 32, 64);
    if (quad == 0) { LSum[w][0][l15] = sred0; LSum[w][1][l15] = sred1; }
    __syncthreads();
    if (t < TI) {
        int u = t >> 5, s = (t >> 4) & 1, il = t & 15;
        float L = (LSum[u * 4 + 0][s][il] + LSum[u * 4 + 1][s][il])
                + (LSum[u * 4 + 2][s][il] + LSum[u * 4 + 3][s][il]);
        Scale[t] = alpha[0] / L;
    }
    __syncthreads();

    #pragma unroll
    for (int nt = 0; nt < 4; nt++) {
        float sc = Scale[nt * 16 + l15];
        int i = i0 + nt * 16 + l15;
        #pragma unroll
        for (int mt = 0; mt < 2; mt++)
            #pragma unroll
            for (int r = 0; r < 4; r++) {
                int c = cblk * 256 + w * 32 + mt * 16 + quad * 4 + r;
                size_t idx = ((size_t)(b * NF + c)) * HW + i;
                out[idx] = x[idx] + sc * acc[mt][nt][r];
            }
    }
}

extern "C" void kernel_launch(void* const* d_in, const int* in_sizes, int n_in,
                              void* d_out, int out_size, void* d_ws, size_t ws_size,
                              hipStream_t stream)
{
    const float* x     = (const float*)d_in[0];
    const float* Wq    = (const float*)d_in[1];
    const float* bq    = (const float*)d_in[2];
    const float* Wk    = (const float*)d_in[3];
    const float* bk    = (const float*)d_in[4];
    const float* Wv    = (const float*)d_in[5];
    const float* bv    = (const float*)d_in[6];
    const float* alpha = (const float*)d_in[7];
    float* out = (float*)d_out;

    char* ws = (char*)d_ws;
    bfu*   xt   = (bfu*)(ws);                                  // [0,16) MB : [b][n][c] bf16
    bfu*   Wb   = (bfu*)(ws + (16u << 20));                    // [16,~16.6) MB: [640][512] bf16
    float* bcat = (float*)(ws + (17u << 20));                  // 2.5 KB at 17 MB
    bfu*   Qb   = (bfu*)(ws + (18u << 20));                    // [18,20) MB : [b][n][64]
    bfu*   Kb   = (bfu*)(ws + (20u << 20));                    // [20,22) MB : [b][n][64]
    bfu*   Vb   = (bfu*)(ws + (22u << 20));                    // [22,38) MB : [b][c][n]  (16 MB)

    k0_pre<<<dim3(2048 + 640), 256, 0, stream>>>(x, xt, Wq, bq, Wk, bk, Wv, bv, Wb, bcat);
    k1_proj<<<dim3(5, HW / 128, BS), 256, 0, stream>>>(Wb, bcat, xt, Qb, Kb, Vb);
    k23_fused<<<dim3(HW / TI * BS * 2), 512, 0, stream>>>(Kb, Qb, Vb, x, alpha, out);
}